// Round 1
// baseline (229.623 us; speedup 1.0000x reference)
//
#include <hip/hip_runtime.h>

// Problem constants (from reference): D=128, P=8, Q=40 (NUM_NEGATIVES=5*P)
#define DIMS   128
#define PNUM   8
#define QNUM   40
#define NBR    48   // P + Q
#define WAVES_PER_BLOCK 4

// Kernel 1: one 64-lane wave per node. Lane j < 48 owns neighbor j
// (j<8 -> pos, else neg). Own row staged in LDS, broadcast-read as float4.
// Each lane computes the full 128-dot in registers, applies sigmoid +
// softplus terms; group-of-8 shuffles give the tuplewise means; a full
// wave reduce + LDS gives one partial per block -> ws[blockIdx].
__global__ __launch_bounds__(256) void node_loss_partial(
    const float* __restrict__ x,
    const int*   __restrict__ pos_idx,
    const int*   __restrict__ neg_idx,
    const int*   __restrict__ h_ptr,
    float*       __restrict__ ws,
    int N)
{
    __shared__ float xn_sh[WAVES_PER_BLOCK][DIMS];
    __shared__ float wsum[WAVES_PER_BLOCK];

    const int wave = threadIdx.x >> 6;   // 0..3
    const int lane = threadIdx.x & 63;   // 0..63
    const int node = blockIdx.x * WAVES_PER_BLOCK + wave;

    // Stage own row x[node] into this wave's LDS slab (32 lanes x float4).
    if (node < N && lane < 32) {
        const float4* row = reinterpret_cast<const float4*>(x + (size_t)node * DIMS);
        reinterpret_cast<float4*>(xn_sh[wave])[lane] = row[lane];
    }
    __syncthreads();

    float v = 0.0f;
    if (node < N) {
        float s = 0.0f;          // sigmoid score for this lane's neighbor
        float pair_part = 0.0f;
        if (lane < NBR) {
            const int nb = (lane < PNUM)
                ? pos_idx[node * PNUM + lane]
                : neg_idx[node * QNUM + (lane - PNUM)];
            const float4* nrow = reinterpret_cast<const float4*>(x + (size_t)nb * DIMS);
            const float4* xn4  = reinterpret_cast<const float4*>(xn_sh[wave]);
            float acc = 0.0f;
#pragma unroll
            for (int t = 0; t < DIMS / 4; ++t) {
                const float4 a = xn4[t];     // LDS broadcast (same addr all lanes)
                const float4 b = nrow[t];    // per-lane gathered row, sequential
                acc += a.x * b.x + a.y * b.y + a.z * b.z + a.w * b.w;
            }
            s = 1.0f / (1.0f + expf(-acc));          // sigmoid (inf-safe)
            const float sp = log1pf(expf(s));        // softplus(s), s in (0,1)
            pair_part = (lane < PNUM) ? (sp - s) : sp;   // label 1 vs 0
        }

        // Group-of-8 sums of s: group 0 = pos mean, groups 1..5 = neg tuple means
        float gs = s;
        gs += __shfl_xor(gs, 1);
        gs += __shfl_xor(gs, 2);
        gs += __shfl_xor(gs, 4);

        float tuple_part = 0.0f;
        if ((lane & 7) == 0 && lane < NBR) {
            const float t  = gs * 0.125f;            // group mean
            const float sp = log1pf(expf(t));
            tuple_part = (lane == 0) ? (sp - t) : sp;
        }

        const int h = *h_ptr;  // broadcast scalar load, cached
        const float pair_scale  = 1.0f / (48.0f * (float)N);
        const float tuple_scale = 1.0f / (6.0f  * (float)(N - h));
        v = pair_part * pair_scale + tuple_part * tuple_scale;
    }

    // Full 64-lane reduce of v
    v += __shfl_xor(v, 1);
    v += __shfl_xor(v, 2);
    v += __shfl_xor(v, 4);
    v += __shfl_xor(v, 8);
    v += __shfl_xor(v, 16);
    v += __shfl_xor(v, 32);

    if (lane == 0) wsum[wave] = v;
    __syncthreads();
    if (threadIdx.x == 0)
        ws[blockIdx.x] = wsum[0] + wsum[1] + wsum[2] + wsum[3];
}

// Kernel 2: deterministic single-block reduction of the per-block partials.
__global__ __launch_bounds__(256) void reduce_final(
    const float* __restrict__ ws, float* __restrict__ out, int nparts)
{
    __shared__ float sm[WAVES_PER_BLOCK];
    float acc = 0.0f;
    for (int i = threadIdx.x; i < nparts; i += 256) acc += ws[i];

    acc += __shfl_xor(acc, 1);
    acc += __shfl_xor(acc, 2);
    acc += __shfl_xor(acc, 4);
    acc += __shfl_xor(acc, 8);
    acc += __shfl_xor(acc, 16);
    acc += __shfl_xor(acc, 32);

    const int wave = threadIdx.x >> 6;
    const int lane = threadIdx.x & 63;
    if (lane == 0) sm[wave] = acc;
    __syncthreads();
    if (threadIdx.x == 0)
        out[0] = sm[0] + sm[1] + sm[2] + sm[3];
}

extern "C" void kernel_launch(void* const* d_in, const int* in_sizes, int n_in,
                              void* d_out, int out_size, void* d_ws, size_t ws_size,
                              hipStream_t stream) {
    const float* x   = (const float*)d_in[0];
    const int*   pos = (const int*)d_in[1];
    const int*   neg = (const int*)d_in[2];
    const int*   h   = (const int*)d_in[3];

    const int N = in_sizes[0] / DIMS;              // 50000
    float* ws = (float*)d_ws;                      // nblocks floats of scratch
    const int nblocks = (N + WAVES_PER_BLOCK - 1) / WAVES_PER_BLOCK;  // 12500

    node_loss_partial<<<nblocks, 256, 0, stream>>>(x, pos, neg, h, ws, N);
    reduce_final<<<1, 256, 0, stream>>>(ws, (float*)d_out, nblocks);
}

// Round 2
// 144.761 us; speedup vs baseline: 1.5862x; 1.5862x over previous
//
#include <hip/hip_runtime.h>
#include <hip/hip_fp16.h>

// Problem constants (from reference): D=128, P=8, Q=40 (NUM_NEGATIVES=5*P)
#define DIMS   128
#define PNUM   8
#define QNUM   40
#define NBR    48   // P + Q
#define WAVES_PER_BLOCK 4

// ---------------------------------------------------------------------------
// Kernel 0 (fp16 path): convert x fp32 -> fp16 into workspace.
// ---------------------------------------------------------------------------
__global__ __launch_bounds__(256) void convert_f32_to_f16(
    const float* __restrict__ x, __half* __restrict__ xh, int nelem4)
{
    const int stride = gridDim.x * blockDim.x;
    for (int i = blockIdx.x * blockDim.x + threadIdx.x; i < nelem4; i += stride) {
        const float4 v = reinterpret_cast<const float4*>(x)[i];
        __half2 h0 = __floats2half2_rn(v.x, v.y);
        __half2 h1 = __floats2half2_rn(v.z, v.w);
        uint2 packed;
        packed.x = *reinterpret_cast<const unsigned int*>(&h0);
        packed.y = *reinterpret_cast<const unsigned int*>(&h1);
        reinterpret_cast<uint2*>(xh)[i] = packed;
    }
}

// ---------------------------------------------------------------------------
// Shared epilogue: given per-lane sigmoid score s (lane<48), produce this
// wave's contribution v summed across lanes, write per-block partial.
// ---------------------------------------------------------------------------
__device__ __forceinline__ float node_epilogue(float s, int lane, int N, int h)
{
    float pair_part = 0.0f;
    if (lane < NBR) {
        const float sp = log1pf(expf(s));            // softplus(s), s in (0,1)
        pair_part = (lane < PNUM) ? (sp - s) : sp;   // label 1 vs 0
    }
    // Group-of-8 sums: group 0 = pos mean, groups 1..5 = neg tuple means
    float gs = s;
    gs += __shfl_xor(gs, 1);
    gs += __shfl_xor(gs, 2);
    gs += __shfl_xor(gs, 4);

    float tuple_part = 0.0f;
    if ((lane & 7) == 0 && lane < NBR) {
        const float t  = gs * 0.125f;
        const float sp = log1pf(expf(t));
        tuple_part = (lane == 0) ? (sp - t) : sp;
    }
    const float pair_scale  = 1.0f / (48.0f * (float)N);
    const float tuple_scale = 1.0f / (6.0f  * (float)(N - h));
    return pair_part * pair_scale + tuple_part * tuple_scale;
}

// ---------------------------------------------------------------------------
// Kernel 1 (fp16 gather path): one wave per node, lane-per-neighbor.
// Own row fp32 in LDS (broadcast reads); neighbor rows gathered fp16
// (256 B/row = 16 x uint4 per lane, all issued before use).
// ---------------------------------------------------------------------------
__global__ __launch_bounds__(256) void node_loss_partial_f16(
    const float*  __restrict__ x,
    const __half* __restrict__ xh,
    const int*    __restrict__ pos_idx,
    const int*    __restrict__ neg_idx,
    const int*    __restrict__ h_ptr,
    float*        __restrict__ ws,
    int N)
{
    __shared__ float xn_sh[WAVES_PER_BLOCK][DIMS];
    __shared__ float wsum[WAVES_PER_BLOCK];

    const int wave = threadIdx.x >> 6;
    const int lane = threadIdx.x & 63;
    const int node = blockIdx.x * WAVES_PER_BLOCK + wave;

    if (node < N && lane < 32) {
        const float4* row = reinterpret_cast<const float4*>(x + (size_t)node * DIMS);
        reinterpret_cast<float4*>(xn_sh[wave])[lane] = row[lane];
    }
    __syncthreads();

    float v = 0.0f;
    if (node < N) {
        float s = 0.0f;
        if (lane < NBR) {
            const int nb = (lane < PNUM)
                ? pos_idx[node * PNUM + lane]
                : neg_idx[node * QNUM + (lane - PNUM)];
            const uint4* nrow = reinterpret_cast<const uint4*>(xh + (size_t)nb * DIMS);

            // Issue all 16 gathered 16B loads before consuming (MLP).
            uint4 b[16];
#pragma unroll
            for (int t = 0; t < 16; ++t) b[t] = nrow[t];

            const float4* xn4 = reinterpret_cast<const float4*>(xn_sh[wave]);
            float acc = 0.0f;
#pragma unroll
            for (int t = 0; t < 16; ++t) {
                const float4 a0 = xn4[2 * t];
                const float4 a1 = xn4[2 * t + 1];
                const __half2* h2 = reinterpret_cast<const __half2*>(&b[t]);
                const float2 f0 = __half22float2(h2[0]);
                const float2 f1 = __half22float2(h2[1]);
                const float2 f2 = __half22float2(h2[2]);
                const float2 f3 = __half22float2(h2[3]);
                acc += a0.x * f0.x + a0.y * f0.y + a0.z * f1.x + a0.w * f1.y;
                acc += a1.x * f2.x + a1.y * f2.y + a1.z * f3.x + a1.w * f3.y;
            }
            s = 1.0f / (1.0f + expf(-acc));
        }
        v = node_epilogue(s, lane, N, *h_ptr);
    }

    v += __shfl_xor(v, 1);
    v += __shfl_xor(v, 2);
    v += __shfl_xor(v, 4);
    v += __shfl_xor(v, 8);
    v += __shfl_xor(v, 16);
    v += __shfl_xor(v, 32);

    if (lane == 0) wsum[wave] = v;
    __syncthreads();
    if (threadIdx.x == 0)
        ws[blockIdx.x] = wsum[0] + wsum[1] + wsum[2] + wsum[3];
}

// ---------------------------------------------------------------------------
// Kernel 1 (fp32 fallback, proven): used only if ws_size is too small.
// ---------------------------------------------------------------------------
__global__ __launch_bounds__(256) void node_loss_partial_f32(
    const float* __restrict__ x,
    const int*   __restrict__ pos_idx,
    const int*   __restrict__ neg_idx,
    const int*   __restrict__ h_ptr,
    float*       __restrict__ ws,
    int N)
{
    __shared__ float xn_sh[WAVES_PER_BLOCK][DIMS];
    __shared__ float wsum[WAVES_PER_BLOCK];

    const int wave = threadIdx.x >> 6;
    const int lane = threadIdx.x & 63;
    const int node = blockIdx.x * WAVES_PER_BLOCK + wave;

    if (node < N && lane < 32) {
        const float4* row = reinterpret_cast<const float4*>(x + (size_t)node * DIMS);
        reinterpret_cast<float4*>(xn_sh[wave])[lane] = row[lane];
    }
    __syncthreads();

    float v = 0.0f;
    if (node < N) {
        float s = 0.0f;
        if (lane < NBR) {
            const int nb = (lane < PNUM)
                ? pos_idx[node * PNUM + lane]
                : neg_idx[node * QNUM + (lane - PNUM)];
            const float4* nrow = reinterpret_cast<const float4*>(x + (size_t)nb * DIMS);
            const float4* xn4  = reinterpret_cast<const float4*>(xn_sh[wave]);
            float acc = 0.0f;
#pragma unroll
            for (int t = 0; t < DIMS / 4; ++t) {
                const float4 a = xn4[t];
                const float4 b = nrow[t];
                acc += a.x * b.x + a.y * b.y + a.z * b.z + a.w * b.w;
            }
            s = 1.0f / (1.0f + expf(-acc));
        }
        v = node_epilogue(s, lane, N, *h_ptr);
    }

    v += __shfl_xor(v, 1);
    v += __shfl_xor(v, 2);
    v += __shfl_xor(v, 4);
    v += __shfl_xor(v, 8);
    v += __shfl_xor(v, 16);
    v += __shfl_xor(v, 32);

    if (lane == 0) wsum[wave] = v;
    __syncthreads();
    if (threadIdx.x == 0)
        ws[blockIdx.x] = wsum[0] + wsum[1] + wsum[2] + wsum[3];
}

// ---------------------------------------------------------------------------
// Kernel 2: deterministic single-block reduction of per-block partials.
// ---------------------------------------------------------------------------
__global__ __launch_bounds__(256) void reduce_final(
    const float* __restrict__ ws, float* __restrict__ out, int nparts)
{
    __shared__ float sm[WAVES_PER_BLOCK];
    float acc = 0.0f;
    for (int i = threadIdx.x; i < nparts; i += 256) acc += ws[i];

    acc += __shfl_xor(acc, 1);
    acc += __shfl_xor(acc, 2);
    acc += __shfl_xor(acc, 4);
    acc += __shfl_xor(acc, 8);
    acc += __shfl_xor(acc, 16);
    acc += __shfl_xor(acc, 32);

    const int wave = threadIdx.x >> 6;
    const int lane = threadIdx.x & 63;
    if (lane == 0) sm[wave] = acc;
    __syncthreads();
    if (threadIdx.x == 0)
        out[0] = sm[0] + sm[1] + sm[2] + sm[3];
}

extern "C" void kernel_launch(void* const* d_in, const int* in_sizes, int n_in,
                              void* d_out, int out_size, void* d_ws, size_t ws_size,
                              hipStream_t stream) {
    const float* x   = (const float*)d_in[0];
    const int*   pos = (const int*)d_in[1];
    const int*   neg = (const int*)d_in[2];
    const int*   h   = (const int*)d_in[3];

    const int N = in_sizes[0] / DIMS;  // 50000
    const int nblocks = (N + WAVES_PER_BLOCK - 1) / WAVES_PER_BLOCK;

    const size_t xh_bytes = (size_t)N * DIMS * sizeof(__half);      // 12.8 MB
    const size_t need     = xh_bytes + (size_t)nblocks * sizeof(float);

    if (ws_size >= need) {
        __half* xh = (__half*)d_ws;
        float*  partials = (float*)((char*)d_ws + xh_bytes);        // 256B-aligned
        const int nelem4 = N * DIMS / 4;
        convert_f32_to_f16<<<2048, 256, 0, stream>>>(x, xh, nelem4);
        node_loss_partial_f16<<<nblocks, 256, 0, stream>>>(x, xh, pos, neg, h, partials, N);
        reduce_final<<<1, 256, 0, stream>>>(partials, (float*)d_out, nblocks);
    } else {
        float* partials = (float*)d_ws;
        node_loss_partial_f32<<<nblocks, 256, 0, stream>>>(x, pos, neg, h, partials, N);
        reduce_final<<<1, 256, 0, stream>>>(partials, (float*)d_out, nblocks);
    }
}

// Round 5
// 73.778 us; speedup vs baseline: 3.1123x; 1.9621x over previous
//
#include <hip/hip_runtime.h>

// Problem constants (from reference): D=128, P=8, Q=40 (NUM_NEGATIVES=5*P)
#define DIMS   128
#define PNUM   8
#define QNUM   40
#define NBR    48   // P + Q
#define WAVES_PER_BLOCK 4

typedef float f32x2 __attribute__((ext_vector_type(2)));

// ---------------------------------------------------------------------------
// Kernel 0: convert x fp32 -> fp8 e4m3 (OCP) into workspace. Row = 128 B.
// ---------------------------------------------------------------------------
__global__ __launch_bounds__(256) void convert_f32_to_f8(
    const float* __restrict__ x, unsigned int* __restrict__ x8, int n8)
{
    const int stride = gridDim.x * blockDim.x;
    for (int i = blockIdx.x * blockDim.x + threadIdx.x; i < n8; i += stride) {
        const float4 v0 = reinterpret_cast<const float4*>(x)[2 * i];
        const float4 v1 = reinterpret_cast<const float4*>(x)[2 * i + 1];
        unsigned int a = __builtin_amdgcn_cvt_pk_fp8_f32(v0.x, v0.y, 0u, false);
        a = __builtin_amdgcn_cvt_pk_fp8_f32(v0.z, v0.w, a, true);
        unsigned int b = __builtin_amdgcn_cvt_pk_fp8_f32(v1.x, v1.y, 0u, false);
        b = __builtin_amdgcn_cvt_pk_fp8_f32(v1.z, v1.w, b, true);
        uint2 o; o.x = a; o.y = b;
        reinterpret_cast<uint2*>(x8)[i] = o;
    }
}

// ---------------------------------------------------------------------------
// Shared epilogue: per-lane sigmoid score s (lane<48) -> this node's loss v.
// ---------------------------------------------------------------------------
__device__ __forceinline__ float node_epilogue(float s, int lane, int N, int h)
{
    float pair_part = 0.0f;
    if (lane < NBR) {
        const float sp = log1pf(expf(s));            // softplus(s), s in (0,1)
        pair_part = (lane < PNUM) ? (sp - s) : sp;   // label 1 vs 0
    }
    // Group-of-8 sums: group 0 = pos mean, groups 1..5 = neg tuple means
    float gs = s;
    gs += __shfl_xor(gs, 1);
    gs += __shfl_xor(gs, 2);
    gs += __shfl_xor(gs, 4);

    float tuple_part = 0.0f;
    if ((lane & 7) == 0 && lane < NBR) {
        const float t  = gs * 0.125f;
        const float sp = log1pf(expf(t));
        tuple_part = (lane == 0) ? (sp - t) : sp;
    }
    const float pair_scale  = 1.0f / (48.0f * (float)N);
    const float tuple_scale = 1.0f / (6.0f  * (float)(N - h));
    return pair_part * pair_scale + tuple_part * tuple_scale;
}

// ---------------------------------------------------------------------------
// Kernel 1 (fp8, 8-lane cooperative): one wave per node. Each fp8 row is
// exactly one 128B cache line; 8 lanes x 16B cover a full row, so every
// gather instruction is 8 fully-coalesced line requests (6 instrs/wave).
// Own-row fp32 fragment (16 floats) lives in registers across all passes.
// ---------------------------------------------------------------------------
__global__ __launch_bounds__(256) void node_loss_partial_f8(
    const float*        __restrict__ x,
    const unsigned int* __restrict__ x8,   // fp8 matrix, 32 uints per row
    const int*          __restrict__ pos_idx,
    const int*          __restrict__ neg_idx,
    const int*          __restrict__ h_ptr,
    float*              __restrict__ ws,
    int N)
{
    __shared__ float scores_sh[WAVES_PER_BLOCK][NBR];
    __shared__ float wsum[WAVES_PER_BLOCK];

    const int wave = threadIdx.x >> 6;
    const int lane = threadIdx.x & 63;
    const int sub  = lane & 7;     // position within 8-lane row group
    const int grp  = lane >> 3;    // which row of the 8 in this pass
    const int node = blockIdx.x * WAVES_PER_BLOCK + wave;

    float v = 0.0f;
    if (node < N) {
        // Own-row fp32 fragment: floats [sub*16 .. sub*16+15] in 4 x float4.
        const float4* own =
            reinterpret_cast<const float4*>(x + (size_t)node * DIMS) + sub * 4;
        float4 a0 = own[0], a1 = own[1], a2 = own[2], a3 = own[3];

        // This lane's neighbor index (lane j < 48 owns neighbor j).
        int my_idx = 0;
        if (lane < NBR)
            my_idx = (lane < PNUM) ? pos_idx[node * PNUM + lane]
                                   : neg_idx[node * QNUM + (lane - PNUM)];

#pragma unroll
        for (int p = 0; p < 6; ++p) {
            // Row handled by this lane's group in pass p.
            const int nb = __shfl(my_idx, p * 8 + grp);
            const uint4 q =
                reinterpret_cast<const uint4*>(x8 + (size_t)nb * 32)[sub];

            float acc = 0.0f;
            {
                const f32x2 lo = __builtin_amdgcn_cvt_pk_f32_fp8(q.x, false);
                const f32x2 hi = __builtin_amdgcn_cvt_pk_f32_fp8(q.x, true);
                acc += a0.x * lo[0] + a0.y * lo[1] + a0.z * hi[0] + a0.w * hi[1];
            }
            {
                const f32x2 lo = __builtin_amdgcn_cvt_pk_f32_fp8(q.y, false);
                const f32x2 hi = __builtin_amdgcn_cvt_pk_f32_fp8(q.y, true);
                acc += a1.x * lo[0] + a1.y * lo[1] + a1.z * hi[0] + a1.w * hi[1];
            }
            {
                const f32x2 lo = __builtin_amdgcn_cvt_pk_f32_fp8(q.z, false);
                const f32x2 hi = __builtin_amdgcn_cvt_pk_f32_fp8(q.z, true);
                acc += a2.x * lo[0] + a2.y * lo[1] + a2.z * hi[0] + a2.w * hi[1];
            }
            {
                const f32x2 lo = __builtin_amdgcn_cvt_pk_f32_fp8(q.w, false);
                const f32x2 hi = __builtin_amdgcn_cvt_pk_f32_fp8(q.w, true);
                acc += a3.x * lo[0] + a3.y * lo[1] + a3.z * hi[0] + a3.w * hi[1];
            }
            // Reduce the 8 partial dots within the group (butterfly).
            acc += __shfl_xor(acc, 1);
            acc += __shfl_xor(acc, 2);
            acc += __shfl_xor(acc, 4);
            if (sub == 0) scores_sh[wave][p * 8 + grp] = acc;
        }

        // Same-wave LDS producer/consumer: DS ops complete in order, no barrier.
        float s = 0.0f;
        if (lane < NBR)
            s = 1.0f / (1.0f + expf(-scores_sh[wave][lane]));
        v = node_epilogue(s, lane, N, *h_ptr);
    }

    v += __shfl_xor(v, 1);
    v += __shfl_xor(v, 2);
    v += __shfl_xor(v, 4);
    v += __shfl_xor(v, 8);
    v += __shfl_xor(v, 16);
    v += __shfl_xor(v, 32);

    if (lane == 0) wsum[wave] = v;
    __syncthreads();
    if (threadIdx.x == 0)
        ws[blockIdx.x] = wsum[0] + wsum[1] + wsum[2] + wsum[3];
}

// ---------------------------------------------------------------------------
// fp32 fallback (proven) if ws_size can't hold the fp8 copy.
// ---------------------------------------------------------------------------
__global__ __launch_bounds__(256) void node_loss_partial_f32(
    const float* __restrict__ x,
    const int*   __restrict__ pos_idx,
    const int*   __restrict__ neg_idx,
    const int*   __restrict__ h_ptr,
    float*       __restrict__ ws,
    int N)
{
    __shared__ float xn_sh[WAVES_PER_BLOCK][DIMS];
    __shared__ float wsum[WAVES_PER_BLOCK];

    const int wave = threadIdx.x >> 6;
    const int lane = threadIdx.x & 63;
    const int node = blockIdx.x * WAVES_PER_BLOCK + wave;

    if (node < N && lane < 32) {
        const float4* row = reinterpret_cast<const float4*>(x + (size_t)node * DIMS);
        reinterpret_cast<float4*>(xn_sh[wave])[lane] = row[lane];
    }
    __syncthreads();

    float v = 0.0f;
    if (node < N) {
        float s = 0.0f;
        if (lane < NBR) {
            const int nb = (lane < PNUM)
                ? pos_idx[node * PNUM + lane]
                : neg_idx[node * QNUM + (lane - PNUM)];
            const float4* nrow = reinterpret_cast<const float4*>(x + (size_t)nb * DIMS);
            const float4* xn4  = reinterpret_cast<const float4*>(xn_sh[wave]);
            float acc = 0.0f;
#pragma unroll
            for (int t = 0; t < DIMS / 4; ++t) {
                const float4 a = xn4[t];
                const float4 b = nrow[t];
                acc += a.x * b.x + a.y * b.y + a.z * b.z + a.w * b.w;
            }
            s = 1.0f / (1.0f + expf(-acc));
        }
        v = node_epilogue(s, lane, N, *h_ptr);
    }

    v += __shfl_xor(v, 1);
    v += __shfl_xor(v, 2);
    v += __shfl_xor(v, 4);
    v += __shfl_xor(v, 8);
    v += __shfl_xor(v, 16);
    v += __shfl_xor(v, 32);

    if (lane == 0) wsum[wave] = v;
    __syncthreads();
    if (threadIdx.x == 0)
        ws[blockIdx.x] = wsum[0] + wsum[1] + wsum[2] + wsum[3];
}

// ---------------------------------------------------------------------------
// Kernel 2: deterministic single-block reduction of per-block partials.
// ---------------------------------------------------------------------------
__global__ __launch_bounds__(256) void reduce_final(
    const float* __restrict__ ws, float* __restrict__ out, int nparts)
{
    __shared__ float sm[WAVES_PER_BLOCK];
    float acc = 0.0f;
    for (int i = threadIdx.x; i < nparts; i += 256) acc += ws[i];

    acc += __shfl_xor(acc, 1);
    acc += __shfl_xor(acc, 2);
    acc += __shfl_xor(acc, 4);
    acc += __shfl_xor(acc, 8);
    acc += __shfl_xor(acc, 16);
    acc += __shfl_xor(acc, 32);

    const int wave = threadIdx.x >> 6;
    const int lane = threadIdx.x & 63;
    if (lane == 0) sm[wave] = acc;
    __syncthreads();
    if (threadIdx.x == 0)
        out[0] = sm[0] + sm[1] + sm[2] + sm[3];
}

extern "C" void kernel_launch(void* const* d_in, const int* in_sizes, int n_in,
                              void* d_out, int out_size, void* d_ws, size_t ws_size,
                              hipStream_t stream) {
    const float* x   = (const float*)d_in[0];
    const int*   pos = (const int*)d_in[1];
    const int*   neg = (const int*)d_in[2];
    const int*   h   = (const int*)d_in[3];

    const int N = in_sizes[0] / DIMS;  // 50000
    const int nblocks = (N + WAVES_PER_BLOCK - 1) / WAVES_PER_BLOCK;

    const size_t x8_bytes = (size_t)N * DIMS;  // 6.4 MB (1 B/elem)
    const size_t need     = x8_bytes + (size_t)nblocks * sizeof(float);

    if (ws_size >= need) {
        unsigned int* x8 = (unsigned int*)d_ws;
        float* partials  = (float*)((char*)d_ws + x8_bytes);  // 128B-aligned
        const int n8 = N * DIMS / 8;
        convert_f32_to_f8<<<2048, 256, 0, stream>>>(x, x8, n8);
        node_loss_partial_f8<<<nblocks, 256, 0, stream>>>(x, x8, pos, neg, h, partials, N);
        reduce_final<<<1, 256, 0, stream>>>(partials, (float*)d_out, nblocks);
    } else {
        float* partials = (float*)d_ws;
        node_loss_partial_f32<<<nblocks, 256, 0, stream>>>(x, pos, neg, h, partials, N);
        reduce_final<<<1, 256, 0, stream>>>(partials, (float*)d_out, nblocks);
    }
}